// Round 1
// baseline (685.365 us; speedup 1.0000x reference)
//
#include <hip/hip_runtime.h>
#include <cstdint>

// ---------------------------------------------------------------------------
// GCN: bx = relu(GCNConv(x,W1,b1)); cx = relu(GCNConv(bx,W2,b2));
//      px = segment_max(cx,batch); out = px@Wm + bm
// GCNConv(h) = dis[d]*sum_e dis[src]*h[src] + h[d]*dis[d]^2 + b,
//   dis = rsqrt(in_deg+1)
// ---------------------------------------------------------------------------

__global__ void count_deg_k(const int* __restrict__ dst, int* __restrict__ deg, int E) {
  int e = blockIdx.x * blockDim.x + threadIdx.x;
  if (e < E) atomicAdd(&deg[dst[e]], 1);
}

__global__ void dis_k(const int* __restrict__ deg, float* __restrict__ dis, int n) {
  int i = blockIdx.x * blockDim.x + threadIdx.x;
  if (i < n) dis[i] = 1.0f / sqrtf((float)deg[i] + 1.0f);
}

__global__ void scan1_k(const int* __restrict__ deg, int* __restrict__ blksum, int n) {
  __shared__ int sd[256];
  int i = blockIdx.x * 256 + threadIdx.x;
  sd[threadIdx.x] = (i < n) ? deg[i] : 0;
  __syncthreads();
  for (int s = 128; s > 0; s >>= 1) {
    if (threadIdx.x < s) sd[threadIdx.x] += sd[threadIdx.x + s];
    __syncthreads();
  }
  if (threadIdx.x == 0) blksum[blockIdx.x] = sd[0];
}

// single block, nb <= 256
__global__ void scan2_k(const int* __restrict__ blksum, int* __restrict__ blkoff, int nb) {
  __shared__ int sd[256];
  int v = (threadIdx.x < nb) ? blksum[threadIdx.x] : 0;
  sd[threadIdx.x] = v;
  __syncthreads();
  for (int d = 1; d < 256; d <<= 1) {
    int t = (threadIdx.x >= d) ? sd[threadIdx.x - d] : 0;
    __syncthreads();
    sd[threadIdx.x] += t;
    __syncthreads();
  }
  if (threadIdx.x < nb) blkoff[threadIdx.x] = sd[threadIdx.x] - v;  // exclusive
}

__global__ void scan3_k(const int* __restrict__ deg, const int* __restrict__ blkoff,
                        int* __restrict__ offs, int n) {
  __shared__ int sd[256];
  int i = blockIdx.x * 256 + threadIdx.x;
  int v = (i < n) ? deg[i] : 0;
  sd[threadIdx.x] = v;
  __syncthreads();
  for (int d = 1; d < 256; d <<= 1) {
    int t = (threadIdx.x >= d) ? sd[threadIdx.x - d] : 0;
    __syncthreads();
    sd[threadIdx.x] += t;
    __syncthreads();
  }
  if (i < n) offs[i] = blkoff[blockIdx.x] + sd[threadIdx.x] - v;
  if (i == n - 1) offs[n] = blkoff[blockIdx.x] + sd[threadIdx.x];
}

__global__ void fill_csr_k(const int* __restrict__ src, const int* __restrict__ dst,
                           const int* __restrict__ offs, int* __restrict__ cursor,
                           int* __restrict__ csr, int E) {
  int e = blockIdx.x * blockDim.x + threadIdx.x;
  if (e >= E) return;
  int d = dst[e];
  int pos = atomicAdd(&cursor[d], 1);
  csr[offs[d] + pos] = src[e];
}

// ---------------------------------------------------------------------------
// fp32 GEMM: C[M,N] = A[M,K] @ B[K,N].  BM=BN=128, BK=16, 256 thr, 8x8/thr.
// ---------------------------------------------------------------------------
#define BMT 128
#define BNT 128
#define BKT 16
#define LDP 136  // padded LDS stride (544 B: 16B-aligned float4, 2-way bank alias)

__global__ __launch_bounds__(256) void gemm_f32(const float* __restrict__ A,
                                                const float* __restrict__ B,
                                                float* __restrict__ C,
                                                int M, int N, int K) {
  __shared__ float As[BKT][LDP];  // transposed: As[k][r]
  __shared__ float Bs[BKT][LDP];  // Bs[k][c]
  const int tid = threadIdx.x;
  const int row0 = blockIdx.x * BMT;
  const int col0 = blockIdx.y * BNT;
  const int tx = tid & 15, ty = tid >> 4;

  float acc[8][8] = {};

  const int arow = tid >> 2;         // 0..63
  const int acol = (tid & 3) * 4;    // k sub-offset
  const int brow = tid >> 5;         // 0..7
  const int bcol = (tid & 31) * 4;

  for (int k0 = 0; k0 < K; k0 += BKT) {
#pragma unroll
    for (int h = 0; h < 2; ++h) {
      int r = arow + h * 64;
      int gr = row0 + r;
      float4 v = make_float4(0.f, 0.f, 0.f, 0.f);
      if (gr < M) v = *(const float4*)&A[(size_t)gr * K + k0 + acol];
      As[acol + 0][r] = v.x;
      As[acol + 1][r] = v.y;
      As[acol + 2][r] = v.z;
      As[acol + 3][r] = v.w;
    }
#pragma unroll
    for (int h = 0; h < 2; ++h) {
      int kk = brow + h * 8;
      float4 v = *(const float4*)&B[(size_t)(k0 + kk) * N + col0 + bcol];
      *(float4*)&Bs[kk][bcol] = v;
    }
    __syncthreads();
#pragma unroll
    for (int kk = 0; kk < BKT; ++kk) {
      float a[8], b[8];
      *(float4*)&a[0] = *(const float4*)&As[kk][ty * 8];
      *(float4*)&a[4] = *(const float4*)&As[kk][ty * 8 + 4];
      *(float4*)&b[0] = *(const float4*)&Bs[kk][tx * 8];
      *(float4*)&b[4] = *(const float4*)&Bs[kk][tx * 8 + 4];
#pragma unroll
      for (int i = 0; i < 8; ++i)
#pragma unroll
        for (int j = 0; j < 8; ++j)
          acc[i][j] = fmaf(a[i], b[j], acc[i][j]);
    }
    __syncthreads();
  }

#pragma unroll
  for (int i = 0; i < 8; ++i) {
    int gr = row0 + ty * 8 + i;
    if (gr < M) {
      *(float4*)&C[(size_t)gr * N + col0 + tx * 8 + 0] = *(float4*)&acc[i][0];
      *(float4*)&C[(size_t)gr * N + col0 + tx * 8 + 4] = *(float4*)&acc[i][4];
    }
  }
}

// ---------------------------------------------------------------------------
// Aggregation + self-loop + bias + relu.  One wave per node, V ch/lane.
// ---------------------------------------------------------------------------
template <int C>
__global__ __launch_bounds__(256) void agg_k(const float* __restrict__ h,
                                             const float* __restrict__ dis,
                                             const int* __restrict__ offs,
                                             const int* __restrict__ csr,
                                             const float* __restrict__ bias,
                                             float* __restrict__ out, int n) {
  constexpr int V = C / 64;
  int wid = (blockIdx.x * blockDim.x + threadIdx.x) >> 6;
  int lane = threadIdx.x & 63;
  if (wid >= n) return;
  const int co = lane * V;

  float acc[V];
#pragma unroll
  for (int v = 0; v < V; ++v) acc[v] = 0.f;

  const int beg = offs[wid], end = offs[wid + 1];
  for (int j = beg; j < end; ++j) {
    int s = csr[j];
    float w = dis[s];
    const float* hp = h + (size_t)s * C + co;
    if constexpr (V == 4) {
      float4 hv = *(const float4*)hp;
      acc[0] = fmaf(hv.x, w, acc[0]);
      acc[1] = fmaf(hv.y, w, acc[1]);
      acc[2] = fmaf(hv.z, w, acc[2]);
      acc[3] = fmaf(hv.w, w, acc[3]);
    } else {
      float2 hv = *(const float2*)hp;
      acc[0] = fmaf(hv.x, w, acc[0]);
      acc[1] = fmaf(hv.y, w, acc[1]);
    }
  }

  const float di = dis[wid];
  const float* hp = h + (size_t)wid * C + co;
  float slf[V];
  if constexpr (V == 4) {
    float4 hv = *(const float4*)hp;
    slf[0] = hv.x; slf[1] = hv.y; slf[2] = hv.z; slf[3] = hv.w;
  } else {
    float2 hv = *(const float2*)hp;
    slf[0] = hv.x; slf[1] = hv.y;
  }

  float res[V];
#pragma unroll
  for (int v = 0; v < V; ++v) {
    float t = acc[v] * di + slf[v] * (di * di) + bias[co + v];
    res[v] = fmaxf(t, 0.f);
  }
  float* op = out + (size_t)wid * C + co;
  if constexpr (V == 4) {
    *(float4*)op = make_float4(res[0], res[1], res[2], res[3]);
  } else {
    *(float2*)op = make_float2(res[0], res[1]);
  }
}

// ---------------------------------------------------------------------------
// Global max pool over sorted batch ids. 64 blocks x 128 ch. relu'd input >=0.
// ---------------------------------------------------------------------------
__global__ void pool_max_k(const float* __restrict__ cx, const int* __restrict__ batch,
                           float* __restrict__ px, int n) {
  __shared__ int bounds[2];
  int g = blockIdx.x;
  if (threadIdx.x < 2) {
    int target = g + (int)threadIdx.x;  // lower_bound(batch, target)
    int lo = 0, hi = n;
    while (lo < hi) {
      int mid = (lo + hi) >> 1;
      if (batch[mid] < target) lo = mid + 1; else hi = mid;
    }
    bounds[threadIdx.x] = lo;
  }
  __syncthreads();
  int c = threadIdx.x;  // 0..127
  float m = 0.f;
  for (int i = bounds[0]; i < bounds[1]; ++i)
    m = fmaxf(m, cx[(size_t)i * 128 + c]);
  px[g * 128 + c] = m;
}

// out[64,64] = px[64,128] @ Wm[128,64] + bm
__global__ void final_mm_k(const float* __restrict__ px, const float* __restrict__ Wm,
                           const float* __restrict__ bm, float* __restrict__ out) {
  int g = blockIdx.x;
  int c = threadIdx.x;  // 0..63
  float acc = bm[c];
#pragma unroll 8
  for (int k = 0; k < 128; ++k)
    acc = fmaf(px[g * 128 + k], Wm[k * 64 + c], acc);
  out[g * 64 + c] = acc;
}

// ---------------------------------------------------------------------------
extern "C" void kernel_launch(void* const* d_in, const int* in_sizes, int n_in,
                              void* d_out, int out_size, void* d_ws, size_t ws_size,
                              hipStream_t stream) {
  const float* x     = (const float*)d_in[0];
  const int*   ei    = (const int*)d_in[1];
  const int*   batch = (const int*)d_in[2];
  const float* W1    = (const float*)d_in[3];
  const float* b1    = (const float*)d_in[4];
  const float* W2    = (const float*)d_in[5];
  const float* b2    = (const float*)d_in[6];
  const float* Wm    = (const float*)d_in[7];
  const float* bm    = (const float*)d_in[8];
  float* out = (float*)d_out;

  const int E = in_sizes[1] / 2;
  const int n = in_sizes[2];
  const int IN_C = 256, HID = 256, HID2 = 128, NG = 64, NDC = 64;
  (void)NDC;
  const int* src = ei;
  const int* dst = ei + E;

  char* w = (char*)d_ws;
  size_t off = 0;
  auto alloc = [&](size_t bytes) -> void* {
    void* p = w + off;
    off = (off + bytes + 255) & ~(size_t)255;
    return p;
  };
  const int nb = (n + 255) / 256;
  int*   deg    = (int*)alloc((size_t)n * 4);
  int*   cursor = (int*)alloc((size_t)n * 4);
  float* dis    = (float*)alloc((size_t)n * 4);
  int*   offs   = (int*)alloc((size_t)(n + 1) * 4);
  int*   blksum = (int*)alloc((size_t)nb * 4);
  int*   blkoff = (int*)alloc((size_t)nb * 4);
  int*   csr    = (int*)alloc((size_t)E * 4);
  float* px     = (float*)alloc((size_t)NG * HID2 * 4);
  float* bufA   = (float*)alloc((size_t)n * HID * 4);  // h1, then h2
  float* bufB   = (float*)alloc((size_t)n * HID * 4);  // bx, then cx
  float* h1 = bufA;
  float* bx = bufB;
  float* h2 = bufA;
  float* cx = bufB;

  hipMemsetAsync(deg, 0, (size_t)n * 4, stream);
  hipMemsetAsync(cursor, 0, (size_t)n * 4, stream);

  count_deg_k<<<(E + 255) / 256, 256, 0, stream>>>(dst, deg, E);
  dis_k<<<(n + 255) / 256, 256, 0, stream>>>(deg, dis, n);
  scan1_k<<<nb, 256, 0, stream>>>(deg, blksum, n);
  scan2_k<<<1, 256, 0, stream>>>(blksum, blkoff, nb);
  scan3_k<<<nb, 256, 0, stream>>>(deg, blkoff, offs, n);
  fill_csr_k<<<(E + 255) / 256, 256, 0, stream>>>(src, dst, offs, cursor, csr, E);

  dim3 g1((n + BMT - 1) / BMT, HID / BNT);
  gemm_f32<<<g1, 256, 0, stream>>>(x, W1, h1, n, HID, IN_C);
  agg_k<256><<<(n + 3) / 4, 256, 0, stream>>>(h1, dis, offs, csr, b1, bx, n);

  dim3 g2((n + BMT - 1) / BMT, HID2 / BNT);
  gemm_f32<<<g2, 256, 0, stream>>>(bx, W2, h2, n, HID2, HID);
  agg_k<128><<<(n + 3) / 4, 256, 0, stream>>>(h2, dis, offs, csr, b2, cx, n);

  pool_max_k<<<NG, HID2, 0, stream>>>(cx, batch, px, n);
  final_mm_k<<<NG, 64, 0, stream>>>(px, Wm, bm, out);
}

// Round 2
// 633.569 us; speedup vs baseline: 1.0818x; 1.0818x over previous
//
#include <hip/hip_runtime.h>
#include <cstdint>

// ---------------------------------------------------------------------------
// GCN: bx = relu(GCNConv(x,W1,b1)); cx = relu(GCNConv(bx,W2,b2));
//      px = segment_max(cx,batch); out = px@Wm + bm
// GCNConv(h) = dis[d]*sum_e dis[src]*h[src] + h[d]*dis[d]^2 + b,
//   dis = rsqrt(in_deg+1)
// R1: pool fused into agg2 epilogue via atomicMax on int bits (relu'd >= 0),
//     cx never materialized. pool_max_k deleted.
// ---------------------------------------------------------------------------

__global__ void count_deg_k(const int* __restrict__ dst, int* __restrict__ deg, int E) {
  int e = blockIdx.x * blockDim.x + threadIdx.x;
  if (e < E) atomicAdd(&deg[dst[e]], 1);
}

__global__ void dis_k(const int* __restrict__ deg, float* __restrict__ dis, int n) {
  int i = blockIdx.x * blockDim.x + threadIdx.x;
  if (i < n) dis[i] = 1.0f / sqrtf((float)deg[i] + 1.0f);
}

__global__ void scan1_k(const int* __restrict__ deg, int* __restrict__ blksum, int n) {
  __shared__ int sd[256];
  int i = blockIdx.x * 256 + threadIdx.x;
  sd[threadIdx.x] = (i < n) ? deg[i] : 0;
  __syncthreads();
  for (int s = 128; s > 0; s >>= 1) {
    if (threadIdx.x < s) sd[threadIdx.x] += sd[threadIdx.x + s];
    __syncthreads();
  }
  if (threadIdx.x == 0) blksum[blockIdx.x] = sd[0];
}

// single block, nb <= 256
__global__ void scan2_k(const int* __restrict__ blksum, int* __restrict__ blkoff, int nb) {
  __shared__ int sd[256];
  int v = (threadIdx.x < nb) ? blksum[threadIdx.x] : 0;
  sd[threadIdx.x] = v;
  __syncthreads();
  for (int d = 1; d < 256; d <<= 1) {
    int t = (threadIdx.x >= d) ? sd[threadIdx.x - d] : 0;
    __syncthreads();
    sd[threadIdx.x] += t;
    __syncthreads();
  }
  if (threadIdx.x < nb) blkoff[threadIdx.x] = sd[threadIdx.x] - v;  // exclusive
}

__global__ void scan3_k(const int* __restrict__ deg, const int* __restrict__ blkoff,
                        int* __restrict__ offs, int n) {
  __shared__ int sd[256];
  int i = blockIdx.x * 256 + threadIdx.x;
  int v = (i < n) ? deg[i] : 0;
  sd[threadIdx.x] = v;
  __syncthreads();
  for (int d = 1; d < 256; d <<= 1) {
    int t = (threadIdx.x >= d) ? sd[threadIdx.x - d] : 0;
    __syncthreads();
    sd[threadIdx.x] += t;
    __syncthreads();
  }
  if (i < n) offs[i] = blkoff[blockIdx.x] + sd[threadIdx.x] - v;
  if (i == n - 1) offs[n] = blkoff[blockIdx.x] + sd[threadIdx.x];
}

__global__ void fill_csr_k(const int* __restrict__ src, const int* __restrict__ dst,
                           const int* __restrict__ offs, int* __restrict__ cursor,
                           int* __restrict__ csr, int E) {
  int e = blockIdx.x * blockDim.x + threadIdx.x;
  if (e >= E) return;
  int d = dst[e];
  int pos = atomicAdd(&cursor[d], 1);
  csr[offs[d] + pos] = src[e];
}

// ---------------------------------------------------------------------------
// fp32 GEMM: C[M,N] = A[M,K] @ B[K,N].  BM=BN=128, BK=16, 256 thr, 8x8/thr.
// ---------------------------------------------------------------------------
#define BMT 128
#define BNT 128
#define BKT 16
#define LDP 136  // padded LDS stride (544 B: 16B-aligned float4, 2-way bank alias)

__global__ __launch_bounds__(256) void gemm_f32(const float* __restrict__ A,
                                                const float* __restrict__ B,
                                                float* __restrict__ C,
                                                int M, int N, int K) {
  __shared__ float As[BKT][LDP];  // transposed: As[k][r]
  __shared__ float Bs[BKT][LDP];  // Bs[k][c]
  const int tid = threadIdx.x;
  const int row0 = blockIdx.x * BMT;
  const int col0 = blockIdx.y * BNT;
  const int tx = tid & 15, ty = tid >> 4;

  float acc[8][8] = {};

  const int arow = tid >> 2;         // 0..63
  const int acol = (tid & 3) * 4;    // k sub-offset
  const int brow = tid >> 5;         // 0..7
  const int bcol = (tid & 31) * 4;

  for (int k0 = 0; k0 < K; k0 += BKT) {
#pragma unroll
    for (int h = 0; h < 2; ++h) {
      int r = arow + h * 64;
      int gr = row0 + r;
      float4 v = make_float4(0.f, 0.f, 0.f, 0.f);
      if (gr < M) v = *(const float4*)&A[(size_t)gr * K + k0 + acol];
      As[acol + 0][r] = v.x;
      As[acol + 1][r] = v.y;
      As[acol + 2][r] = v.z;
      As[acol + 3][r] = v.w;
    }
#pragma unroll
    for (int h = 0; h < 2; ++h) {
      int kk = brow + h * 8;
      float4 v = *(const float4*)&B[(size_t)(k0 + kk) * N + col0 + bcol];
      *(float4*)&Bs[kk][bcol] = v;
    }
    __syncthreads();
#pragma unroll
    for (int kk = 0; kk < BKT; ++kk) {
      float a[8], b[8];
      *(float4*)&a[0] = *(const float4*)&As[kk][ty * 8];
      *(float4*)&a[4] = *(const float4*)&As[kk][ty * 8 + 4];
      *(float4*)&b[0] = *(const float4*)&Bs[kk][tx * 8];
      *(float4*)&b[4] = *(const float4*)&Bs[kk][tx * 8 + 4];
#pragma unroll
      for (int i = 0; i < 8; ++i)
#pragma unroll
        for (int j = 0; j < 8; ++j)
          acc[i][j] = fmaf(a[i], b[j], acc[i][j]);
    }
    __syncthreads();
  }

#pragma unroll
  for (int i = 0; i < 8; ++i) {
    int gr = row0 + ty * 8 + i;
    if (gr < M) {
      *(float4*)&C[(size_t)gr * N + col0 + tx * 8 + 0] = *(float4*)&acc[i][0];
      *(float4*)&C[(size_t)gr * N + col0 + tx * 8 + 4] = *(float4*)&acc[i][4];
    }
  }
}

// ---------------------------------------------------------------------------
// Aggregation + self-loop + bias + relu.  One wave per node, V ch/lane.
// POOL: fuse global max pool via atomicMax on int bits (values >= 0 post-relu);
//       out is then px[NG*C] and `batch` selects the row. cx never stored.
// ---------------------------------------------------------------------------
template <int C, bool POOL>
__global__ __launch_bounds__(256) void agg_k(const float* __restrict__ h,
                                             const float* __restrict__ dis,
                                             const int* __restrict__ offs,
                                             const int* __restrict__ csr,
                                             const float* __restrict__ bias,
                                             const int* __restrict__ batch,
                                             float* __restrict__ out, int n) {
  constexpr int V = C / 64;
  int wid = (blockIdx.x * blockDim.x + threadIdx.x) >> 6;
  int lane = threadIdx.x & 63;
  if (wid >= n) return;
  const int co = lane * V;

  float acc[V];
#pragma unroll
  for (int v = 0; v < V; ++v) acc[v] = 0.f;

  const int beg = offs[wid], end = offs[wid + 1];
  for (int j = beg; j < end; ++j) {
    int s = csr[j];
    float w = dis[s];
    const float* hp = h + (size_t)s * C + co;
    if constexpr (V == 4) {
      float4 hv = *(const float4*)hp;
      acc[0] = fmaf(hv.x, w, acc[0]);
      acc[1] = fmaf(hv.y, w, acc[1]);
      acc[2] = fmaf(hv.z, w, acc[2]);
      acc[3] = fmaf(hv.w, w, acc[3]);
    } else {
      float2 hv = *(const float2*)hp;
      acc[0] = fmaf(hv.x, w, acc[0]);
      acc[1] = fmaf(hv.y, w, acc[1]);
    }
  }

  const float di = dis[wid];
  const float* hp = h + (size_t)wid * C + co;
  float slf[V];
  if constexpr (V == 4) {
    float4 hv = *(const float4*)hp;
    slf[0] = hv.x; slf[1] = hv.y; slf[2] = hv.z; slf[3] = hv.w;
  } else {
    float2 hv = *(const float2*)hp;
    slf[0] = hv.x; slf[1] = hv.y;
  }

  float res[V];
#pragma unroll
  for (int v = 0; v < V; ++v) {
    float t = acc[v] * di + slf[v] * (di * di) + bias[co + v];
    res[v] = fmaxf(t, 0.f);
  }

  if constexpr (POOL) {
    const int g = batch[wid];
    int* pp = (int*)(out + (size_t)g * C + co);
#pragma unroll
    for (int v = 0; v < V; ++v)
      atomicMax(&pp[v], __float_as_int(res[v]));  // res >= 0: int order == float order
  } else {
    float* op = out + (size_t)wid * C + co;
    if constexpr (V == 4) {
      *(float4*)op = make_float4(res[0], res[1], res[2], res[3]);
    } else {
      *(float2*)op = make_float2(res[0], res[1]);
    }
  }
}

// out[64,64] = px[64,128] @ Wm[128,64] + bm
__global__ void final_mm_k(const float* __restrict__ px, const float* __restrict__ Wm,
                           const float* __restrict__ bm, float* __restrict__ out) {
  int g = blockIdx.x;
  int c = threadIdx.x;  // 0..63
  float acc = bm[c];
#pragma unroll 8
  for (int k = 0; k < 128; ++k)
    acc = fmaf(px[g * 128 + k], Wm[k * 64 + c], acc);
  out[g * 64 + c] = acc;
}

// ---------------------------------------------------------------------------
extern "C" void kernel_launch(void* const* d_in, const int* in_sizes, int n_in,
                              void* d_out, int out_size, void* d_ws, size_t ws_size,
                              hipStream_t stream) {
  const float* x     = (const float*)d_in[0];
  const int*   ei    = (const int*)d_in[1];
  const int*   batch = (const int*)d_in[2];
  const float* W1    = (const float*)d_in[3];
  const float* b1    = (const float*)d_in[4];
  const float* W2    = (const float*)d_in[5];
  const float* b2    = (const float*)d_in[6];
  const float* Wm    = (const float*)d_in[7];
  const float* bm    = (const float*)d_in[8];
  float* out = (float*)d_out;

  const int E = in_sizes[1] / 2;
  const int n = in_sizes[2];
  const int IN_C = 256, HID = 256, HID2 = 128, NG = 64, NDC = 64;
  (void)NDC; (void)IN_C;
  const int* src = ei;
  const int* dst = ei + E;

  char* w = (char*)d_ws;
  size_t off = 0;
  auto alloc = [&](size_t bytes) -> void* {
    void* p = w + off;
    off = (off + bytes + 255) & ~(size_t)255;
    return p;
  };
  const int nb = (n + 255) / 256;
  int*   deg    = (int*)alloc((size_t)n * 4);
  int*   cursor = (int*)alloc((size_t)n * 4);
  float* dis    = (float*)alloc((size_t)n * 4);
  int*   offs   = (int*)alloc((size_t)(n + 1) * 4);
  int*   blksum = (int*)alloc((size_t)nb * 4);
  int*   blkoff = (int*)alloc((size_t)nb * 4);
  int*   csr    = (int*)alloc((size_t)E * 4);
  float* px     = (float*)alloc((size_t)NG * HID2 * 4);
  float* bufA   = (float*)alloc((size_t)n * HID * 4);  // h1, then h2
  float* bufB   = (float*)alloc((size_t)n * HID * 4);  // bx
  float* h1 = bufA;
  float* bx = bufB;
  float* h2 = bufA;

  hipMemsetAsync(deg, 0, (size_t)n * 4, stream);
  hipMemsetAsync(cursor, 0, (size_t)n * 4, stream);
  hipMemsetAsync(px, 0, (size_t)NG * HID2 * 4, stream);  // relu'd max >= 0

  count_deg_k<<<(E + 255) / 256, 256, 0, stream>>>(dst, deg, E);
  dis_k<<<(n + 255) / 256, 256, 0, stream>>>(deg, dis, n);
  scan1_k<<<nb, 256, 0, stream>>>(deg, blksum, n);
  scan2_k<<<1, 256, 0, stream>>>(blksum, blkoff, nb);
  scan3_k<<<nb, 256, 0, stream>>>(deg, blkoff, offs, n);
  fill_csr_k<<<(E + 255) / 256, 256, 0, stream>>>(src, dst, offs, cursor, csr, E);

  dim3 g1((n + BMT - 1) / BMT, HID / BNT);
  gemm_f32<<<g1, 256, 0, stream>>>(x, W1, h1, n, HID, IN_C);
  agg_k<256, false><<<(n + 3) / 4, 256, 0, stream>>>(h1, dis, offs, csr, b1, nullptr, bx, n);

  dim3 g2((n + BMT - 1) / BMT, HID2 / BNT);
  gemm_f32<<<g2, 256, 0, stream>>>(bx, W2, h2, n, HID2, HID);
  // agg2 + fused global-max-pool straight into px
  agg_k<128, true><<<(n + 3) / 4, 256, 0, stream>>>(h2, dis, offs, csr, b2, batch, px, n);

  final_mm_k<<<NG, 64, 0, stream>>>(px, Wm, bm, out);
}

// Round 3
// 436.640 us; speedup vs baseline: 1.5696x; 1.4510x over previous
//
#include <hip/hip_runtime.h>
#include <cstdint>
#include <type_traits>

// ---------------------------------------------------------------------------
// GCN: bx = relu(GCNConv(x,W1,b1)); cx = relu(GCNConv(bx,W2,b2));
//      px = segment_max(cx,batch); out = px@Wm + bm
// GCNConv(h) = dis[d]*sum_e dis[src]*h[src] + h[d]*dis[d]^2 + b
// R1: pool fused into agg2 (atomicMax on int bits, relu'd >= 0)
// R2: hidden path in fp16 (error budget 8.8e-3 >> fp16 ~1e-3):
//     - GEMMs via mfma_f32_16x16x32_f16, frag-linear LDS + global_load_lds(16)
//     - agg gathers fp16 (half bytes) + unroll-4 edge loop (4x MLP)
// ---------------------------------------------------------------------------

typedef _Float16 half4v __attribute__((ext_vector_type(4)));
typedef _Float16 half2v __attribute__((ext_vector_type(2)));
typedef _Float16 half8v __attribute__((ext_vector_type(8)));
typedef float f32x4 __attribute__((ext_vector_type(4)));

__device__ __forceinline__ void gl_lds16(const void* g, void* l) {
  __builtin_amdgcn_global_load_lds(
      (const __attribute__((address_space(1))) unsigned int*)g,
      (__attribute__((address_space(3))) unsigned int*)l, 16, 0, 0);
}

// ------------------------------- CSR build ---------------------------------
__global__ void count_deg_k(const int* __restrict__ dst, int* __restrict__ deg, int E) {
  int e = blockIdx.x * blockDim.x + threadIdx.x;
  if (e < E) atomicAdd(&deg[dst[e]], 1);
}

__global__ void dis_k(const int* __restrict__ deg, float* __restrict__ dis, int n) {
  int i = blockIdx.x * blockDim.x + threadIdx.x;
  if (i < n) dis[i] = 1.0f / sqrtf((float)deg[i] + 1.0f);
}

__global__ void scan1_k(const int* __restrict__ deg, int* __restrict__ blksum, int n) {
  __shared__ int sd[256];
  int i = blockIdx.x * 256 + threadIdx.x;
  sd[threadIdx.x] = (i < n) ? deg[i] : 0;
  __syncthreads();
  for (int s = 128; s > 0; s >>= 1) {
    if (threadIdx.x < s) sd[threadIdx.x] += sd[threadIdx.x + s];
    __syncthreads();
  }
  if (threadIdx.x == 0) blksum[blockIdx.x] = sd[0];
}

__global__ void scan2_k(const int* __restrict__ blksum, int* __restrict__ blkoff, int nb) {
  __shared__ int sd[256];
  int v = (threadIdx.x < nb) ? blksum[threadIdx.x] : 0;
  sd[threadIdx.x] = v;
  __syncthreads();
  for (int d = 1; d < 256; d <<= 1) {
    int t = (threadIdx.x >= d) ? sd[threadIdx.x - d] : 0;
    __syncthreads();
    sd[threadIdx.x] += t;
    __syncthreads();
  }
  if (threadIdx.x < nb) blkoff[threadIdx.x] = sd[threadIdx.x] - v;  // exclusive
}

__global__ void scan3_k(const int* __restrict__ deg, const int* __restrict__ blkoff,
                        int* __restrict__ offs, int n) {
  __shared__ int sd[256];
  int i = blockIdx.x * 256 + threadIdx.x;
  int v = (i < n) ? deg[i] : 0;
  sd[threadIdx.x] = v;
  __syncthreads();
  for (int d = 1; d < 256; d <<= 1) {
    int t = (threadIdx.x >= d) ? sd[threadIdx.x - d] : 0;
    __syncthreads();
    sd[threadIdx.x] += t;
    __syncthreads();
  }
  if (i < n) offs[i] = blkoff[blockIdx.x] + sd[threadIdx.x] - v;
  if (i == n - 1) offs[n] = blkoff[blockIdx.x] + sd[threadIdx.x];
}

__global__ void fill_csr_k(const int* __restrict__ src, const int* __restrict__ dst,
                           const int* __restrict__ offs, int* __restrict__ cursor,
                           int* __restrict__ csr, int E) {
  int e = blockIdx.x * blockDim.x + threadIdx.x;
  if (e >= E) return;
  int d = dst[e];
  int pos = atomicAdd(&cursor[d], 1);
  csr[offs[d] + pos] = src[e];
}

// ------------------------------ conversions --------------------------------
__global__ void cvt_x_k(const float* __restrict__ in, _Float16* __restrict__ out, int n4) {
  int i = blockIdx.x * blockDim.x + threadIdx.x;
  if (i < n4) {
    float4 v = ((const float4*)in)[i];
    half4v o = {(_Float16)v.x, (_Float16)v.y, (_Float16)v.z, (_Float16)v.w};
    ((half4v*)out)[i] = o;
  }
}

// W[K][N] fp32 -> Wt[N][K] fp16
__global__ void cvtT_k(const float* __restrict__ W, _Float16* __restrict__ Wt, int K, int N) {
  int idx = blockIdx.x * 256 + threadIdx.x;
  if (idx < K * N) {
    int k = idx / N, c = idx - k * N;
    Wt[(size_t)c * K + k] = (_Float16)W[idx];
  }
}

// ---------------------------------------------------------------------------
// fp16 NT GEMM via MFMA: C[M,N] = A[M,K] @ Bt[N,K]^T, fp32 accumulate.
// BM=BN=128, BK=32, 256 thr (4 waves 2x2), each wave 64x64 = 4x4 frags 16x16.
// LDS frag-linear: slot(frag_lin, lane) at byte frag_lin*1024 + lane*16, holding
// A[row][k..k+7] with row=(fl>>2)*64+(fl&3)*16+(lane&15), k=(lane>>4)*8.
// Staged with global_load_lds(16B): linear LDS dest, pre-permuted global src.
// ds_read_b128 is then perfectly lane-linear: zero bank conflicts.
// ---------------------------------------------------------------------------
#define GBM 128
#define GBN 128
#define GBK 32

__global__ __launch_bounds__(256) void gemm_f16(const _Float16* __restrict__ A,
                                                const _Float16* __restrict__ Bt,
                                                _Float16* __restrict__ C,
                                                int M, int N, int K) {
  __shared__ _Float16 As[GBM * GBK];  // 8KB
  __shared__ _Float16 Bs[GBN * GBK];  // 8KB
  const int tid = threadIdx.x;
  const int lane = tid & 63;
  const int wave = tid >> 6;  // 0..3
  const int wm = wave >> 1, wn = wave & 1;
  const int row0 = blockIdx.x * GBM;
  const int col0 = blockIdx.y * GBN;

  f32x4 acc[4][4] = {};

  // staging sources (2 A-slots + 2 B-slots per thread), hoisted
  const int kbase = (lane >> 4) * 8;
  const _Float16* aSrc[2];
  _Float16* aDst[2];
  const _Float16* bSrc[2];
  _Float16* bDst[2];
#pragma unroll
  for (int h = 0; h < 2; ++h) {
    int fl = h * 4 + wave;
    int row = h * 64 + wave * 16 + (lane & 15);  // (fl>>2)*64 + (fl&3)*16 + lane%16
    int gr = row0 + row;
    if (gr > M - 1) gr = M - 1;  // clamp; those C rows are never written
    aSrc[h] = A + (size_t)gr * K + kbase;
    aDst[h] = As + fl * 512;  // 512 halfs = 1024B per frag-group
    int gc = col0 + row;      // same in-tile pattern for B (N % 128 == 0)
    bSrc[h] = Bt + (size_t)gc * K + kbase;
    bDst[h] = Bs + fl * 512;
  }

  for (int k0 = 0; k0 < K; k0 += GBK) {
    gl_lds16(aSrc[0] + k0, aDst[0]);
    gl_lds16(aSrc[1] + k0, aDst[1]);
    gl_lds16(bSrc[0] + k0, bDst[0]);
    gl_lds16(bSrc[1] + k0, bDst[1]);
    __syncthreads();  // drains vmcnt before reads

    half8v af[4], bf[4];
#pragma unroll
    for (int m = 0; m < 4; ++m)
      af[m] = *(const half8v*)(As + (wm * 4 + m) * 512 + lane * 8);
#pragma unroll
    for (int nj = 0; nj < 4; ++nj)
      bf[nj] = *(const half8v*)(Bs + (wn * 4 + nj) * 512 + lane * 8);
#pragma unroll
    for (int m = 0; m < 4; ++m)
#pragma unroll
      for (int nj = 0; nj < 4; ++nj)
        acc[m][nj] = __builtin_amdgcn_mfma_f32_16x16x32_f16(af[m], bf[nj], acc[m][nj], 0, 0, 0);
    __syncthreads();
  }

  // epilogue: C/D layout col=lane&15, row=(lane>>4)*4+r (guide m89, dtype-indep)
#pragma unroll
  for (int m = 0; m < 4; ++m) {
#pragma unroll
    for (int nj = 0; nj < 4; ++nj) {
      int col = col0 + wn * 64 + nj * 16 + (lane & 15);
#pragma unroll
      for (int r = 0; r < 4; ++r) {
        int row = row0 + wm * 64 + m * 16 + (lane >> 4) * 4 + r;
        if (row < M) C[(size_t)row * N + col] = (_Float16)acc[m][nj][r];
      }
    }
  }
}

// ---------------------------------------------------------------------------
// Aggregation + self-loop + bias + relu. One wave/node, V=C/64 fp16 ch/lane.
// Edge loop unrolled x4 -> 4 independent outstanding gathers (latency-bound fix).
// POOL: fused global max pool via atomicMax on int bits into fp32 px.
// ---------------------------------------------------------------------------
template <int C, bool POOL>
__global__ __launch_bounds__(256) void agg_k(const _Float16* __restrict__ h,
                                             const float* __restrict__ dis,
                                             const int* __restrict__ offs,
                                             const int* __restrict__ csr,
                                             const float* __restrict__ bias,
                                             const int* __restrict__ batch,
                                             void* __restrict__ outv, int n) {
  constexpr int V = C / 64;
  using hvec = std::conditional_t<V == 4, half4v, half2v>;
  int wid = (blockIdx.x * blockDim.x + threadIdx.x) >> 6;
  int lane = threadIdx.x & 63;
  if (wid >= n) return;
  const int co = lane * V;

  float acc[V] = {};
  const int beg = offs[wid], end = offs[wid + 1];
  int j = beg;
  for (; j + 4 <= end; j += 4) {
    int s0 = csr[j], s1 = csr[j + 1], s2 = csr[j + 2], s3 = csr[j + 3];
    float w0 = dis[s0], w1 = dis[s1], w2 = dis[s2], w3 = dis[s3];
    hvec v0 = *(const hvec*)(h + (size_t)s0 * C + co);
    hvec v1 = *(const hvec*)(h + (size_t)s1 * C + co);
    hvec v2 = *(const hvec*)(h + (size_t)s2 * C + co);
    hvec v3 = *(const hvec*)(h + (size_t)s3 * C + co);
#pragma unroll
    for (int v = 0; v < V; ++v) {
      acc[v] = fmaf((float)v0[v], w0, acc[v]);
      acc[v] = fmaf((float)v1[v], w1, acc[v]);
      acc[v] = fmaf((float)v2[v], w2, acc[v]);
      acc[v] = fmaf((float)v3[v], w3, acc[v]);
    }
  }
  for (; j < end; ++j) {
    int s = csr[j];
    float w = dis[s];
    hvec hv = *(const hvec*)(h + (size_t)s * C + co);
#pragma unroll
    for (int v = 0; v < V; ++v) acc[v] = fmaf((float)hv[v], w, acc[v]);
  }

  const float di = dis[wid];
  hvec sv = *(const hvec*)(h + (size_t)wid * C + co);
  float res[V];
#pragma unroll
  for (int v = 0; v < V; ++v) {
    float t = acc[v] * di + (float)sv[v] * (di * di) + bias[co + v];
    res[v] = fmaxf(t, 0.f);
  }

  if constexpr (POOL) {
    const int g = batch[wid];
    int* pp = (int*)((float*)outv + (size_t)g * C + co);
#pragma unroll
    for (int v = 0; v < V; ++v)
      atomicMax(&pp[v], __float_as_int(res[v]));  // res >= 0: int order == float order
  } else {
    _Float16* op = (_Float16*)outv + (size_t)wid * C + co;
    hvec r;
#pragma unroll
    for (int v = 0; v < V; ++v) r[v] = (_Float16)res[v];
    *(hvec*)op = r;
  }
}

// out[64,64] = px[64,128] @ Wm[128,64] + bm   (fp32)
__global__ void final_mm_k(const float* __restrict__ px, const float* __restrict__ Wm,
                           const float* __restrict__ bm, float* __restrict__ out) {
  int g = blockIdx.x;
  int c = threadIdx.x;  // 0..63
  float acc = bm[c];
#pragma unroll 8
  for (int k = 0; k < 128; ++k)
    acc = fmaf(px[g * 128 + k], Wm[k * 64 + c], acc);
  out[g * 64 + c] = acc;
}

// ---------------------------------------------------------------------------
extern "C" void kernel_launch(void* const* d_in, const int* in_sizes, int n_in,
                              void* d_out, int out_size, void* d_ws, size_t ws_size,
                              hipStream_t stream) {
  const float* x     = (const float*)d_in[0];
  const int*   ei    = (const int*)d_in[1];
  const int*   batch = (const int*)d_in[2];
  const float* W1    = (const float*)d_in[3];
  const float* b1    = (const float*)d_in[4];
  const float* W2    = (const float*)d_in[5];
  const float* b2    = (const float*)d_in[6];
  const float* Wm    = (const float*)d_in[7];
  const float* bm    = (const float*)d_in[8];
  float* out = (float*)d_out;

  const int E = in_sizes[1] / 2;
  const int n = in_sizes[2];
  const int IN_C = 256, HID = 256, HID2 = 128, NG = 64;
  const int* src = ei;
  const int* dst = ei + E;

  char* w = (char*)d_ws;
  size_t off = 0;
  auto alloc = [&](size_t bytes) -> void* {
    void* p = w + off;
    off = (off + bytes + 255) & ~(size_t)255;
    return p;
  };
  const int nb = (n + 255) / 256;
  int*      deg    = (int*)alloc((size_t)n * 4);
  int*      cursor = (int*)alloc((size_t)n * 4);
  float*    dis    = (float*)alloc((size_t)n * 4);
  int*      offs   = (int*)alloc((size_t)(n + 1) * 4);
  int*      blksum = (int*)alloc((size_t)nb * 4);
  int*      blkoff = (int*)alloc((size_t)nb * 4);
  int*      csr    = (int*)alloc((size_t)E * 4);
  float*    px     = (float*)alloc((size_t)NG * HID2 * 4);
  _Float16* xh     = (_Float16*)alloc((size_t)n * IN_C * 2);
  _Float16* Wt1    = (_Float16*)alloc((size_t)HID * IN_C * 2);
  _Float16* Wt2    = (_Float16*)alloc((size_t)HID2 * HID * 2);
  _Float16* bufA   = (_Float16*)alloc((size_t)n * HID * 2);  // h1, then h2
  _Float16* bufB   = (_Float16*)alloc((size_t)n * HID * 2);  // bx
  _Float16* h1 = bufA;
  _Float16* bx = bufB;
  _Float16* h2 = bufA;

  hipMemsetAsync(deg, 0, (size_t)n * 4, stream);
  hipMemsetAsync(cursor, 0, (size_t)n * 4, stream);
  hipMemsetAsync(px, 0, (size_t)NG * HID2 * 4, stream);  // relu'd max >= 0

  count_deg_k<<<(E + 255) / 256, 256, 0, stream>>>(dst, deg, E);
  dis_k<<<(n + 255) / 256, 256, 0, stream>>>(deg, dis, n);
  scan1_k<<<nb, 256, 0, stream>>>(deg, blksum, n);
  scan2_k<<<1, 256, 0, stream>>>(blksum, blkoff, nb);
  scan3_k<<<nb, 256, 0, stream>>>(deg, blkoff, offs, n);
  fill_csr_k<<<(E + 255) / 256, 256, 0, stream>>>(src, dst, offs, cursor, csr, E);

  cvt_x_k<<<(n * IN_C / 4 + 255) / 256, 256, 0, stream>>>(x, xh, n * IN_C / 4);
  cvtT_k<<<(IN_C * HID + 255) / 256, 256, 0, stream>>>(W1, Wt1, IN_C, HID);
  cvtT_k<<<(HID * HID2 + 255) / 256, 256, 0, stream>>>(W2, Wt2, HID, HID2);

  dim3 g1((n + GBM - 1) / GBM, HID / GBN);
  gemm_f16<<<g1, 256, 0, stream>>>(xh, Wt1, h1, n, HID, IN_C);
  agg_k<256, false><<<(n + 3) / 4, 256, 0, stream>>>(h1, dis, offs, csr, b1, nullptr, bx, n);

  dim3 g2((n + GBM - 1) / GBM, HID2 / GBN);
  gemm_f16<<<g2, 256, 0, stream>>>(bx, Wt2, h2, n, HID2, HID);
  agg_k<128, true><<<(n + 3) / 4, 256, 0, stream>>>(h2, dis, offs, csr, b2, batch, px, n);

  final_mm_k<<<NG, 64, 0, stream>>>(px, Wm, bm, out);
}

// Round 4
// 355.164 us; speedup vs baseline: 1.9297x; 1.2294x over previous
//
#include <hip/hip_runtime.h>
#include <cstdint>

// ---------------------------------------------------------------------------
// GCN: bx = relu(GCNConv(x,W1,b1)); cx = relu(GCNConv(bx,W2,b2));
//      px = segment_max(cx,batch); out = px@Wm + bm
// GCNConv(h) = dis[d]*sum_e dis[src]*h[src] + h[d]*dis[d]^2 + b
// R1: pool fused into agg2 (atomicMax on int bits, relu'd >= 0)
// R2: fp16 hidden path; MFMA GEMMs; agg unroll-4
// R3: agg rework for latency: multi-edge-per-wave 16B gathers (4 edges/load at
//     C=128, 2 at C=256), unroll-4 => 16 gathers in flight; shfl_xor reduce;
//     block-level LDS pool combine => 4x fewer device-scope atomics.
// ---------------------------------------------------------------------------

typedef _Float16 half4v __attribute__((ext_vector_type(4)));
typedef _Float16 half8v __attribute__((ext_vector_type(8)));
typedef float f32x4 __attribute__((ext_vector_type(4)));

__device__ __forceinline__ void gl_lds16(const void* g, void* l) {
  __builtin_amdgcn_global_load_lds(
      (const __attribute__((address_space(1))) unsigned int*)g,
      (__attribute__((address_space(3))) unsigned int*)l, 16, 0, 0);
}

// ------------------------------- CSR build ---------------------------------
__global__ void count_deg_k(const int* __restrict__ dst, int* __restrict__ deg, int E) {
  int e = blockIdx.x * blockDim.x + threadIdx.x;
  if (e < E) atomicAdd(&deg[dst[e]], 1);
}

__global__ void dis_k(const int* __restrict__ deg, float* __restrict__ dis, int n) {
  int i = blockIdx.x * blockDim.x + threadIdx.x;
  if (i < n) dis[i] = 1.0f / sqrtf((float)deg[i] + 1.0f);
}

__global__ void scan1_k(const int* __restrict__ deg, int* __restrict__ blksum, int n) {
  __shared__ int sd[256];
  int i = blockIdx.x * 256 + threadIdx.x;
  sd[threadIdx.x] = (i < n) ? deg[i] : 0;
  __syncthreads();
  for (int s = 128; s > 0; s >>= 1) {
    if (threadIdx.x < s) sd[threadIdx.x] += sd[threadIdx.x + s];
    __syncthreads();
  }
  if (threadIdx.x == 0) blksum[blockIdx.x] = sd[0];
}

__global__ void scan2_k(const int* __restrict__ blksum, int* __restrict__ blkoff, int nb) {
  __shared__ int sd[256];
  int v = (threadIdx.x < nb) ? blksum[threadIdx.x] : 0;
  sd[threadIdx.x] = v;
  __syncthreads();
  for (int d = 1; d < 256; d <<= 1) {
    int t = (threadIdx.x >= d) ? sd[threadIdx.x - d] : 0;
    __syncthreads();
    sd[threadIdx.x] += t;
    __syncthreads();
  }
  if (threadIdx.x < nb) blkoff[threadIdx.x] = sd[threadIdx.x] - v;  // exclusive
}

__global__ void scan3_k(const int* __restrict__ deg, const int* __restrict__ blkoff,
                        int* __restrict__ offs, int n) {
  __shared__ int sd[256];
  int i = blockIdx.x * 256 + threadIdx.x;
  int v = (i < n) ? deg[i] : 0;
  sd[threadIdx.x] = v;
  __syncthreads();
  for (int d = 1; d < 256; d <<= 1) {
    int t = (threadIdx.x >= d) ? sd[threadIdx.x - d] : 0;
    __syncthreads();
    sd[threadIdx.x] += t;
    __syncthreads();
  }
  if (i < n) offs[i] = blkoff[blockIdx.x] + sd[threadIdx.x] - v;
  if (i == n - 1) offs[n] = blkoff[blockIdx.x] + sd[threadIdx.x];
}

__global__ void fill_csr_k(const int* __restrict__ src, const int* __restrict__ dst,
                           const int* __restrict__ offs, int* __restrict__ cursor,
                           int* __restrict__ csr, int E) {
  int e = blockIdx.x * blockDim.x + threadIdx.x;
  if (e >= E) return;
  int d = dst[e];
  int pos = atomicAdd(&cursor[d], 1);
  csr[offs[d] + pos] = src[e];
}

// ------------------------------ conversions --------------------------------
__global__ void cvt_x_k(const float* __restrict__ in, _Float16* __restrict__ out, int n4) {
  int i = blockIdx.x * blockDim.x + threadIdx.x;
  if (i < n4) {
    float4 v = ((const float4*)in)[i];
    half4v o = {(_Float16)v.x, (_Float16)v.y, (_Float16)v.z, (_Float16)v.w};
    ((half4v*)out)[i] = o;
  }
}

// W[K][N] fp32 -> Wt[N][K] fp16
__global__ void cvtT_k(const float* __restrict__ W, _Float16* __restrict__ Wt, int K, int N) {
  int idx = blockIdx.x * 256 + threadIdx.x;
  if (idx < K * N) {
    int k = idx / N, c = idx - k * N;
    Wt[(size_t)c * K + k] = (_Float16)W[idx];
  }
}

// ---------------------------------------------------------------------------
// fp16 NT GEMM via MFMA: C[M,N] = A[M,K] @ Bt[N,K]^T, fp32 accumulate.
// BM=BN=128, BK=32, 256 thr (4 waves 2x2), each wave 64x64 = 4x4 frags 16x16.
// Frag-linear LDS staged via global_load_lds(16B), zero bank conflicts.
// ---------------------------------------------------------------------------
#define GBM 128
#define GBN 128
#define GBK 32

__global__ __launch_bounds__(256) void gemm_f16(const _Float16* __restrict__ A,
                                                const _Float16* __restrict__ Bt,
                                                _Float16* __restrict__ C,
                                                int M, int N, int K) {
  __shared__ _Float16 As[GBM * GBK];  // 8KB
  __shared__ _Float16 Bs[GBN * GBK];  // 8KB
  const int tid = threadIdx.x;
  const int lane = tid & 63;
  const int wave = tid >> 6;  // 0..3
  const int wm = wave >> 1, wn = wave & 1;
  const int row0 = blockIdx.x * GBM;
  const int col0 = blockIdx.y * GBN;

  f32x4 acc[4][4] = {};

  const int kbase = (lane >> 4) * 8;
  const _Float16* aSrc[2];
  _Float16* aDst[2];
  const _Float16* bSrc[2];
  _Float16* bDst[2];
#pragma unroll
  for (int h = 0; h < 2; ++h) {
    int fl = h * 4 + wave;
    int row = h * 64 + wave * 16 + (lane & 15);
    int gr = row0 + row;
    if (gr > M - 1) gr = M - 1;  // clamp; those C rows are never written
    aSrc[h] = A + (size_t)gr * K + kbase;
    aDst[h] = As + fl * 512;
    int gc = col0 + row;
    bSrc[h] = Bt + (size_t)gc * K + kbase;
    bDst[h] = Bs + fl * 512;
  }

  for (int k0 = 0; k0 < K; k0 += GBK) {
    gl_lds16(aSrc[0] + k0, aDst[0]);
    gl_lds16(aSrc[1] + k0, aDst[1]);
    gl_lds16(bSrc[0] + k0, bDst[0]);
    gl_lds16(bSrc[1] + k0, bDst[1]);
    __syncthreads();

    half8v af[4], bf[4];
#pragma unroll
    for (int m = 0; m < 4; ++m)
      af[m] = *(const half8v*)(As + (wm * 4 + m) * 512 + lane * 8);
#pragma unroll
    for (int nj = 0; nj < 4; ++nj)
      bf[nj] = *(const half8v*)(Bs + (wn * 4 + nj) * 512 + lane * 8);
#pragma unroll
    for (int m = 0; m < 4; ++m)
#pragma unroll
      for (int nj = 0; nj < 4; ++nj)
        acc[m][nj] = __builtin_amdgcn_mfma_f32_16x16x32_f16(af[m], bf[nj], acc[m][nj], 0, 0, 0);
    __syncthreads();
  }

#pragma unroll
  for (int m = 0; m < 4; ++m) {
#pragma unroll
    for (int nj = 0; nj < 4; ++nj) {
      int col = col0 + wn * 64 + nj * 16 + (lane & 15);
#pragma unroll
      for (int r = 0; r < 4; ++r) {
        int row = row0 + wm * 64 + m * 16 + (lane >> 4) * 4 + r;
        if (row < M) C[(size_t)row * N + col] = (_Float16)acc[m][nj][r];
      }
    }
  }
}

// ---------------------------------------------------------------------------
// Aggregation + self-loop + bias + relu. One wave/node, 4 nodes/block.
// Wave splits into EPW = 64/(C/8) edge-slots; each lane gathers half8v (16B).
// Unroll-4 => EPW*4 edges in flight per wave. shfl_xor cross-slot reduce.
// POOL: block-level LDS max combine (batch-sorted => ~all blocks single-graph)
//       then ONE atomicMax per channel per block; per-node fallback at graph
//       boundaries.
// ---------------------------------------------------------------------------
template <int C, bool POOL>
__global__ __launch_bounds__(256) void agg_k(const _Float16* __restrict__ h,
                                             const float* __restrict__ dis,
                                             const int* __restrict__ offs,
                                             const int* __restrict__ csr,
                                             const float* __restrict__ bias,
                                             const int* __restrict__ batch,
                                             void* __restrict__ outv, int n) {
  constexpr int LPR = C / 8;    // lanes per row (16 or 32)
  constexpr int EPW = 64 / LPR; // edge slots per wave (4 or 2)
  const int tid = threadIdx.x;
  const int lane = tid & 63;
  const int wave = tid >> 6;
  const int slot = lane / LPR;
  const int ch0 = (lane % LPR) * 8;

  const int wid = blockIdx.x * 4 + wave;
  const bool valid = wid < n;
  const int node = valid ? wid : n - 1;

  const int beg = offs[node], end = offs[node + 1];
  float acc[8] = {};
  for (int jb = beg; jb < end; jb += EPW * 4) {
#pragma unroll
    for (int u = 0; u < 4; ++u) {
      int e = jb + u * EPW + slot;
      int ec = e < end ? e : end - 1;
      int s = csr[ec];
      float w = (e < end) ? dis[s] : 0.f;
      half8v hv = *(const half8v*)(h + (size_t)s * C + ch0);
#pragma unroll
      for (int v = 0; v < 8; ++v) acc[v] = fmaf((float)hv[v], w, acc[v]);
    }
  }

  // cross-slot reduce: after this every lane holds totals for its ch0 block
  if constexpr (EPW == 4) {
#pragma unroll
    for (int v = 0; v < 8; ++v) {
      acc[v] += __shfl_xor(acc[v], 16);
      acc[v] += __shfl_xor(acc[v], 32);
    }
  } else {
#pragma unroll
    for (int v = 0; v < 8; ++v) acc[v] += __shfl_xor(acc[v], 32);
  }

  const float di = dis[node];
  half8v sv = *(const half8v*)(h + (size_t)node * C + ch0);
  float4 blo = *(const float4*)(bias + ch0);
  float4 bhi = *(const float4*)(bias + ch0 + 4);
  const float bb[8] = {blo.x, blo.y, blo.z, blo.w, bhi.x, bhi.y, bhi.z, bhi.w};
  float res[8];
#pragma unroll
  for (int v = 0; v < 8; ++v)
    res[v] = fmaxf(acc[v] * di + (float)sv[v] * (di * di) + bb[v], 0.f);

  if constexpr (!POOL) {
    if (valid && lane < LPR) {
      half8v r;
#pragma unroll
      for (int v = 0; v < 8; ++v) r[v] = (_Float16)res[v];
      *(half8v*)((_Float16*)outv + (size_t)node * C + ch0) = r;
    }
  } else {
    __shared__ float pres[4][C];
    __shared__ int pg[4];
    __shared__ int uni;
    const int g = valid ? batch[node] : -1 - wave;  // distinct => forces fallback
    if (lane < LPR) {
      *(f32x4*)&pres[wave][ch0] = f32x4{res[0], res[1], res[2], res[3]};
      *(f32x4*)&pres[wave][ch0 + 4] = f32x4{res[4], res[5], res[6], res[7]};
    }
    if (lane == 0) pg[wave] = g;
    __syncthreads();
    if (tid == 0) uni = (pg[0] == pg[1] && pg[1] == pg[2] && pg[2] == pg[3] && pg[0] >= 0);
    __syncthreads();
    float* px = (float*)outv;
    if (uni) {
      if (tid < C) {
        float m = fmaxf(fmaxf(pres[0][tid], pres[1][tid]),
                        fmaxf(pres[2][tid], pres[3][tid]));
        atomicMax((int*)&px[(size_t)pg[0] * C + tid], __float_as_int(m));
      }
    } else {
#pragma unroll
      for (int wv = 0; wv < 4; ++wv) {
        int gg = pg[wv];
        if (gg >= 0 && tid < C)
          atomicMax((int*)&px[(size_t)gg * C + tid], __float_as_int(pres[wv][tid]));
      }
    }
  }
}

// out[64,64] = px[64,128] @ Wm[128,64] + bm   (fp32)
__global__ void final_mm_k(const float* __restrict__ px, const float* __restrict__ Wm,
                           const float* __restrict__ bm, float* __restrict__ out) {
  int g = blockIdx.x;
  int c = threadIdx.x;  // 0..63
  float acc = bm[c];
#pragma unroll 8
  for (int k = 0; k < 128; ++k)
    acc = fmaf(px[g * 128 + k], Wm[k * 64 + c], acc);
  out[g * 64 + c] = acc;
}

// ---------------------------------------------------------------------------
extern "C" void kernel_launch(void* const* d_in, const int* in_sizes, int n_in,
                              void* d_out, int out_size, void* d_ws, size_t ws_size,
                              hipStream_t stream) {
  const float* x     = (const float*)d_in[0];
  const int*   ei    = (const int*)d_in[1];
  const int*   batch = (const int*)d_in[2];
  const float* W1    = (const float*)d_in[3];
  const float* b1    = (const float*)d_in[4];
  const float* W2    = (const float*)d_in[5];
  const float* b2    = (const float*)d_in[6];
  const float* Wm    = (const float*)d_in[7];
  const float* bm    = (const float*)d_in[8];
  float* out = (float*)d_out;

  const int E = in_sizes[1] / 2;
  const int n = in_sizes[2];
  const int IN_C = 256, HID = 256, HID2 = 128, NG = 64;
  const int* src = ei;
  const int* dst = ei + E;

  char* w = (char*)d_ws;
  size_t off = 0;
  auto alloc = [&](size_t bytes) -> void* {
    void* p = w + off;
    off = (off + bytes + 255) & ~(size_t)255;
    return p;
  };
  const int nb = (n + 255) / 256;
  int*      deg    = (int*)alloc((size_t)n * 4);
  int*      cursor = (int*)alloc((size_t)n * 4);
  float*    dis    = (float*)alloc((size_t)n * 4);
  int*      offs   = (int*)alloc((size_t)(n + 1) * 4);
  int*      blksum = (int*)alloc((size_t)nb * 4);
  int*      blkoff = (int*)alloc((size_t)nb * 4);
  int*      csr    = (int*)alloc((size_t)E * 4);
  float*    px     = (float*)alloc((size_t)NG * HID2 * 4);
  _Float16* xh     = (_Float16*)alloc((size_t)n * IN_C * 2);
  _Float16* Wt1    = (_Float16*)alloc((size_t)HID * IN_C * 2);
  _Float16* Wt2    = (_Float16*)alloc((size_t)HID2 * HID * 2);
  _Float16* bufA   = (_Float16*)alloc((size_t)n * HID * 2);  // h1, then h2
  _Float16* bufB   = (_Float16*)alloc((size_t)n * HID * 2);  // bx
  _Float16* h1 = bufA;
  _Float16* bx = bufB;
  _Float16* h2 = bufA;

  hipMemsetAsync(deg, 0, (size_t)n * 4, stream);
  hipMemsetAsync(cursor, 0, (size_t)n * 4, stream);
  hipMemsetAsync(px, 0, (size_t)NG * HID2 * 4, stream);  // relu'd max >= 0

  count_deg_k<<<(E + 255) / 256, 256, 0, stream>>>(dst, deg, E);
  dis_k<<<(n + 255) / 256, 256, 0, stream>>>(deg, dis, n);
  scan1_k<<<nb, 256, 0, stream>>>(deg, blksum, n);
  scan2_k<<<1, 256, 0, stream>>>(blksum, blkoff, nb);
  scan3_k<<<nb, 256, 0, stream>>>(deg, blkoff, offs, n);
  fill_csr_k<<<(E + 255) / 256, 256, 0, stream>>>(src, dst, offs, cursor, csr, E);

  cvt_x_k<<<(n * IN_C / 4 + 255) / 256, 256, 0, stream>>>(x, xh, n * IN_C / 4);
  cvtT_k<<<(IN_C * HID + 255) / 256, 256, 0, stream>>>(W1, Wt1, IN_C, HID);
  cvtT_k<<<(HID * HID2 + 255) / 256, 256, 0, stream>>>(W2, Wt2, HID, HID2);

  dim3 g1((n + GBM - 1) / GBM, HID / GBN);
  gemm_f16<<<g1, 256, 0, stream>>>(xh, Wt1, h1, n, HID, IN_C);
  agg_k<256, false><<<(n + 3) / 4, 256, 0, stream>>>(h1, dis, offs, csr, b1, nullptr, bx, n);

  dim3 g2((n + GBM - 1) / GBM, HID2 / GBN);
  gemm_f16<<<g2, 256, 0, stream>>>(bx, Wt2, h2, n, HID2, HID);
  agg_k<128, true><<<(n + 3) / 4, 256, 0, stream>>>(h2, dis, offs, csr, b2, batch, px, n);

  final_mm_k<<<NG, 64, 0, stream>>>(px, Wm, bm, out);
}